// Round 8
// baseline (976.701 us; speedup 1.0000x reference)
//
#include <hip/hip_runtime.h>
#include <hip/hip_bf16.h>

// Decoder_21208548508049 — round 8.
// Phase A: GEMM1 (exact f32 FMA chain, round-6-verbatim per (t,e)) + LIF ->
//   spike bitmask. NEW: 2 tokens per block (256 thr, 4 waves) so both token
//   halves share W loads via L1 -> W L2 traffic halves; occupancy ~2x.
// Phase B: GEMM2 via bf16 MFMA, A-frags in-register from global x + LDS mask
//   (round-7-verified path; LDS-staged-g machinery permanently excluded).
//   B-frags from bf16-transposed Wt (d_ws) or direct f32 Wr fallback.
//
// T=32,B=8,N=256,D=512. Block = 2 (b,n) tokens, 256 threads. Grid = 1024.
// LDS: xs[2][8][512] f32 (32KB) + msk[2][512] (4KB) = 36KB -> 4 blocks/CU.

#define TT 32
#define CH 8     // t-chunk for phase A
#define BB 8
#define NN 256
#define DD 512

typedef __attribute__((ext_vector_type(8))) short short8;
typedef __attribute__((ext_vector_type(4))) float f32x4;

__device__ __forceinline__ unsigned short f2bf(float f) {
    __hip_bfloat16 h = __float2bfloat16(f);
    return *reinterpret_cast<unsigned short*>(&h);
}

// ---- pre-kernel: Wt[p][d] = bf16(Wr[d][p]) ----
__global__ void cast_transpose_wr(const float* __restrict__ Wr,
                                  unsigned short* __restrict__ Wt) {
    int idx = blockIdx.x * 256 + threadIdx.x;      // 0..262143
    int d = idx >> 9;
    int p = idx & 511;
    Wt[p * DD + d] = f2bf(Wr[idx]);
}

template<bool UW>
__global__ __launch_bounds__(256, 4) void lif_decoder_v8(
    const float* __restrict__ x,      // [T,B,N,D]
    const float* __restrict__ tr_mx,  // [B,N,D]
    const float* __restrict__ Wl,     // [D,D]
    const float* __restrict__ bl,     // [D]
    const float* __restrict__ Wr,     // [D,D]
    const float* __restrict__ br,     // [D]
    const unsigned short* __restrict__ Wt,  // [D,D] bf16 transposed (if UW)
    float* __restrict__ out)          // [T,B,N,D]
{
    __shared__ __align__(16) float xs[2 * CH * DD];    // 32 KB: 2 tokens x t-chunk
    __shared__ __align__(16) unsigned msk[2 * DD];     // 4 KB: (msk[q][d]>>t)&1

    const int tid = threadIdx.x;          // 0..255
    const int tg  = tid >> 7;             // token within block (0/1)
    const int tl  = tid & 127;
    const int e0  = tl * 4;               // owned e-columns (within own token)
    const int tok = blockIdx.x * 2 + tg;
    const size_t base = (size_t)tok * DD;
    const size_t st   = (size_t)BB * NN * DD;   // t-stride

    // ================= Phase A: GEMM1 + LIF =================
    {
        float acc[CH][4];
        float4 m4 = *reinterpret_cast<const float4*>(&tr_mx[base + e0]);
        float m[4] = {m4.x, m4.y, m4.z, m4.w};
        unsigned mc[4] = {0u, 0u, 0u, 0u};

        const float4 blv = *reinterpret_cast<const float4*>(&bl[e0]);
        const float blr[4] = {blv.x, blv.y, blv.z, blv.w};

        #pragma unroll 1
        for (int tgc = 0; tgc < 4; ++tgc) {
            // stage x[tgc*8..+7][both tokens][0..511]: 8 float4/thread, coalesced
            #pragma unroll
            for (int r = 0; r < 8; ++r) {
                const int flat = r * 256 + tid;        // 0..2047
                const int q    = flat >> 10;           // token 0/1
                const int rem  = flat & 1023;
                const int trow = rem >> 7;             // 0..7
                const int c4   = rem & 127;
                const float4 v = *reinterpret_cast<const float4*>(
                    &x[(size_t)(tgc * CH + trow) * st
                       + (size_t)(blockIdx.x * 2 + q) * DD + c4 * 4]);
                *reinterpret_cast<float4*>(&xs[(q * CH + trow) * DD + c4 * 4]) = v;
            }
            __syncthreads();

            #pragma unroll
            for (int i = 0; i < CH; ++i)
                #pragma unroll
                for (int e = 0; e < 4; ++e) acc[i][e] = blr[e];

            const float* xsl = &xs[tg * CH * DD];   // own token's tile

            #pragma unroll 2
            for (int d = 0; d < DD; d += 4) {
                const float4 w0 = *reinterpret_cast<const float4*>(&Wl[(size_t)(d + 0) * DD + e0]);
                const float4 w1 = *reinterpret_cast<const float4*>(&Wl[(size_t)(d + 1) * DD + e0]);
                const float4 w2 = *reinterpret_cast<const float4*>(&Wl[(size_t)(d + 2) * DD + e0]);
                const float4 w3 = *reinterpret_cast<const float4*>(&Wl[(size_t)(d + 3) * DD + e0]);
                #pragma unroll
                for (int i = 0; i < CH; ++i) {
                    const float4 xv = *reinterpret_cast<const float4*>(&xsl[i * DD + d]);
                    // d-ascending fmaf chain per (t,e): identical to r1/4/5/6 passes
                    acc[i][0] = fmaf(xv.x, w0.x, acc[i][0]);
                    acc[i][1] = fmaf(xv.x, w0.y, acc[i][1]);
                    acc[i][2] = fmaf(xv.x, w0.z, acc[i][2]);
                    acc[i][3] = fmaf(xv.x, w0.w, acc[i][3]);
                    acc[i][0] = fmaf(xv.y, w1.x, acc[i][0]);
                    acc[i][1] = fmaf(xv.y, w1.y, acc[i][1]);
                    acc[i][2] = fmaf(xv.y, w1.z, acc[i][2]);
                    acc[i][3] = fmaf(xv.y, w1.w, acc[i][3]);
                    acc[i][0] = fmaf(xv.z, w2.x, acc[i][0]);
                    acc[i][1] = fmaf(xv.z, w2.y, acc[i][1]);
                    acc[i][2] = fmaf(xv.z, w2.z, acc[i][2]);
                    acc[i][3] = fmaf(xv.z, w2.w, acc[i][3]);
                    acc[i][0] = fmaf(xv.w, w3.x, acc[i][0]);
                    acc[i][1] = fmaf(xv.w, w3.y, acc[i][1]);
                    acc[i][2] = fmaf(xv.w, w3.z, acc[i][2]);
                    acc[i][3] = fmaf(xv.w, w3.w, acc[i][3]);
                }
            }
            __syncthreads();   // xs reads done before next chunk overwrites

            // LIF for this chunk (arithmetic identical to prior passes)
            #pragma unroll
            for (int i = 0; i < CH; ++i) {
                const int t = tgc * CH + i;
                #pragma unroll
                for (int e = 0; e < 4; ++e) {
                    m[e] = m[e] + (acc[i][e] - m[e]) * 0.5f;
                    const float s = (m[e] - 1.0f > 0.0f) ? 1.0f : 0.0f;
                    mc[e] |= (s > 0.0f) ? (1u << t) : 0u;
                    m[e] *= (1.0f - s);
                }
            }
        }

        #pragma unroll
        for (int e = 0; e < 4; ++e) msk[tg * DD + e0 + e] = mc[e];
    }
    __syncthreads();

    // ================= Phase B: GEMM2 via bf16 MFMA =================
    // wave wv: token (wv>>1), t-half (wv&1). Round-7-verified per-wave path.
    {
        const int wv   = tid >> 6;            // 0..3
        const int lane = tid & 63;
        const int qB   = wv >> 1;             // token within block
        const int hB   = wv & 1;              // t-half
        const int lcol = lane & 15;
        const int lkg  = lane >> 4;           // 0..3
        const int tA   = hB * 16 + lcol;      // A-frag row (t) this lane supplies
        const size_t baseB = (size_t)(blockIdx.x * 2 + qB) * DD;
        const unsigned* mq = &msk[qB * DD];

        // --- build all 16 A-frags in-register from global x + LDS mask bits ---
        short8 af[16];
        #pragma unroll
        for (int ks = 0; ks < 16; ++ks) {
            const int kb = ks * 32 + lkg * 8;
            const float4 x0 = *reinterpret_cast<const float4*>(&x[(size_t)tA * st + baseB + kb]);
            const float4 x1 = *reinterpret_cast<const float4*>(&x[(size_t)tA * st + baseB + kb + 4]);
            const uint4 m0 = *reinterpret_cast<const uint4*>(&mq[kb]);
            const uint4 m1 = *reinterpret_cast<const uint4*>(&mq[kb + 4]);
            short8 a;
            a[0] = (short)f2bf(((m0.x >> tA) & 1u) ? 0.0f : x0.x);
            a[1] = (short)f2bf(((m0.y >> tA) & 1u) ? 0.0f : x0.y);
            a[2] = (short)f2bf(((m0.z >> tA) & 1u) ? 0.0f : x0.z);
            a[3] = (short)f2bf(((m0.w >> tA) & 1u) ? 0.0f : x0.w);
            a[4] = (short)f2bf(((m1.x >> tA) & 1u) ? 0.0f : x1.x);
            a[5] = (short)f2bf(((m1.y >> tA) & 1u) ? 0.0f : x1.y);
            a[6] = (short)f2bf(((m1.z >> tA) & 1u) ? 0.0f : x1.z);
            a[7] = (short)f2bf(((m1.w >> tA) & 1u) ? 0.0f : x1.w);
            af[ks] = a;
        }

        // --- 4 passes of 128 output cols; acc[8] tiles of 16 cols each ---
        #pragma unroll 1
        for (int pass = 0; pass < 4; ++pass) {
            const int colb = pass * 128;
            f32x4 acc[8];
            #pragma unroll
            for (int nt = 0; nt < 8; ++nt) {
                const float b = br[colb + nt * 16 + lcol];
                acc[nt] = (f32x4){b, b, b, b};
            }

            #pragma unroll
            for (int ks = 0; ks < 16; ++ks) {
                const int kb = ks * 32 + lkg * 8;
                #pragma unroll
                for (int nt = 0; nt < 8; ++nt) {
                    const int col = colb + nt * 16 + lcol;
                    short8 bf;
                    if (UW) {
                        bf = *reinterpret_cast<const short8*>(&Wt[(size_t)col * DD + kb]);
                    } else {
                        #pragma unroll
                        for (int j = 0; j < 8; ++j)
                            bf[j] = (short)f2bf(Wr[(size_t)(kb + j) * DD + col]);
                    }
                    acc[nt] = __builtin_amdgcn_mfma_f32_16x16x32_bf16(af[ks], bf, acc[nt], 0, 0, 0);
                }
            }

            // epilogue: C/D layout col=lane&15, row=(lane>>4)*4+r (verified r7)
            #pragma unroll
            for (int nt = 0; nt < 8; ++nt) {
                const int col = colb + nt * 16 + lcol;
                #pragma unroll
                for (int r = 0; r < 4; ++r) {
                    const int t = hB * 16 + lkg * 4 + r;
                    out[(size_t)t * st + baseB + col] = acc[nt][r];
                }
            }
        }
    }
}

extern "C" void kernel_launch(void* const* d_in, const int* in_sizes, int n_in,
                              void* d_out, int out_size, void* d_ws, size_t ws_size,
                              hipStream_t stream) {
    const float* x     = (const float*)d_in[0];
    const float* tr_mx = (const float*)d_in[1];
    const float* Wl    = (const float*)d_in[2];
    const float* bl    = (const float*)d_in[3];
    const float* Wr    = (const float*)d_in[4];
    const float* br    = (const float*)d_in[5];
    float* out = (float*)d_out;

    const size_t wt_bytes = (size_t)DD * DD * 2;
    dim3 grid(BB * NN / 2);   // 1024 two-token blocks
    dim3 block(256);

    if (ws_size >= wt_bytes) {
        unsigned short* Wt = (unsigned short*)d_ws;
        cast_transpose_wr<<<dim3(1024), dim3(256), 0, stream>>>(Wr, Wt);
        lif_decoder_v8<true><<<grid, block, 0, stream>>>(x, tr_mx, Wl, bl, Wr, br, Wt, out);
    } else {
        lif_decoder_v8<false><<<grid, block, 0, stream>>>(x, tr_mx, Wl, bl, Wr, br, nullptr, out);
    }
}

// Round 9
// 782.328 us; speedup vs baseline: 1.2485x; 1.2485x over previous
//
#include <hip/hip_runtime.h>
#include <hip/hip_bf16.h>

// Decoder_21208548508049 — round 9 = round 8 with the allocator unchained.
// r8's regression was __launch_bounds__(256,4): compiler targets 64 VGPR
// (five-round pattern: arg2=4 -> 64 VGPR; arg2=2 -> 128+) and spilled phase B's
// ~140-reg live set (FETCH 731MB/WRITE 598MB of scratch). Fix: (256,2).
//
// Phase A: GEMM1 exact f32 FMA chain (bit-identical spikes, r1/4/5/6-proven) +
//   LIF -> bitmask. 2 tokens/block share Wl loads -> per-CU L2 traffic halved.
// Phase B: GEMM2 bf16 MFMA, A-frags in-register from global x + LDS mask
//   (r7-verified; absmax 0.03125 = pure bf16 quantization).
//
// T=32,B=8,N=256,D=512. Block = 2 tokens, 256 threads (4 waves). Grid = 1024.
// LDS: xs[2][8][512] f32 (32KB) + msk[2][512] (4KB) = 36KB.

#define TT 32
#define CH 8     // t-chunk for phase A
#define BB 8
#define NN 256
#define DD 512

typedef __attribute__((ext_vector_type(8))) short short8;
typedef __attribute__((ext_vector_type(4))) float f32x4;

__device__ __forceinline__ unsigned short f2bf(float f) {
    __hip_bfloat16 h = __float2bfloat16(f);
    return *reinterpret_cast<unsigned short*>(&h);
}

// ---- pre-kernel: Wt[p][d] = bf16(Wr[d][p]) ----
__global__ void cast_transpose_wr(const float* __restrict__ Wr,
                                  unsigned short* __restrict__ Wt) {
    int idx = blockIdx.x * 256 + threadIdx.x;      // 0..262143
    int d = idx >> 9;
    int p = idx & 511;
    Wt[p * DD + d] = f2bf(Wr[idx]);
}

template<bool UW>
__global__ __launch_bounds__(256, 2) void lif_decoder_v9(
    const float* __restrict__ x,      // [T,B,N,D]
    const float* __restrict__ tr_mx,  // [B,N,D]
    const float* __restrict__ Wl,     // [D,D]
    const float* __restrict__ bl,     // [D]
    const float* __restrict__ Wr,     // [D,D]
    const float* __restrict__ br,     // [D]
    const unsigned short* __restrict__ Wt,  // [D,D] bf16 transposed (if UW)
    float* __restrict__ out)          // [T,B,N,D]
{
    __shared__ __align__(16) float xs[2 * CH * DD];    // 32 KB: 2 tokens x t-chunk
    __shared__ __align__(16) unsigned msk[2 * DD];     // 4 KB: (msk[q][d]>>t)&1

    const int tid = threadIdx.x;          // 0..255
    const int tg  = tid >> 7;             // token within block (0/1)
    const int tl  = tid & 127;
    const int e0  = tl * 4;               // owned e-columns (within own token)
    const int tok = blockIdx.x * 2 + tg;
    const size_t base = (size_t)tok * DD;
    const size_t st   = (size_t)BB * NN * DD;   // t-stride

    // ================= Phase A: GEMM1 + LIF =================
    {
        float acc[CH][4];
        float4 m4 = *reinterpret_cast<const float4*>(&tr_mx[base + e0]);
        float m[4] = {m4.x, m4.y, m4.z, m4.w};
        unsigned mc[4] = {0u, 0u, 0u, 0u};

        const float4 blv = *reinterpret_cast<const float4*>(&bl[e0]);
        const float blr[4] = {blv.x, blv.y, blv.z, blv.w};

        #pragma unroll 1
        for (int tgc = 0; tgc < 4; ++tgc) {
            // stage x[tgc*8..+7][both tokens][0..511]: 8 float4/thread, coalesced
            #pragma unroll
            for (int r = 0; r < 8; ++r) {
                const int flat = r * 256 + tid;        // 0..2047
                const int q    = flat >> 10;           // token 0/1
                const int rem  = flat & 1023;
                const int trow = rem >> 7;             // 0..7
                const int c4   = rem & 127;
                const float4 v = *reinterpret_cast<const float4*>(
                    &x[(size_t)(tgc * CH + trow) * st
                       + (size_t)(blockIdx.x * 2 + q) * DD + c4 * 4]);
                *reinterpret_cast<float4*>(&xs[(q * CH + trow) * DD + c4 * 4]) = v;
            }
            __syncthreads();

            #pragma unroll
            for (int i = 0; i < CH; ++i)
                #pragma unroll
                for (int e = 0; e < 4; ++e) acc[i][e] = blr[e];

            const float* xsl = &xs[tg * CH * DD];   // own token's tile

            #pragma unroll 2
            for (int d = 0; d < DD; d += 4) {
                const float4 w0 = *reinterpret_cast<const float4*>(&Wl[(size_t)(d + 0) * DD + e0]);
                const float4 w1 = *reinterpret_cast<const float4*>(&Wl[(size_t)(d + 1) * DD + e0]);
                const float4 w2 = *reinterpret_cast<const float4*>(&Wl[(size_t)(d + 2) * DD + e0]);
                const float4 w3 = *reinterpret_cast<const float4*>(&Wl[(size_t)(d + 3) * DD + e0]);
                #pragma unroll
                for (int i = 0; i < CH; ++i) {
                    const float4 xv = *reinterpret_cast<const float4*>(&xsl[i * DD + d]);
                    // d-ascending fmaf chain per (t,e): identical to r1/4/5/6 passes
                    acc[i][0] = fmaf(xv.x, w0.x, acc[i][0]);
                    acc[i][1] = fmaf(xv.x, w0.y, acc[i][1]);
                    acc[i][2] = fmaf(xv.x, w0.z, acc[i][2]);
                    acc[i][3] = fmaf(xv.x, w0.w, acc[i][3]);
                    acc[i][0] = fmaf(xv.y, w1.x, acc[i][0]);
                    acc[i][1] = fmaf(xv.y, w1.y, acc[i][1]);
                    acc[i][2] = fmaf(xv.y, w1.z, acc[i][2]);
                    acc[i][3] = fmaf(xv.y, w1.w, acc[i][3]);
                    acc[i][0] = fmaf(xv.z, w2.x, acc[i][0]);
                    acc[i][1] = fmaf(xv.z, w2.y, acc[i][1]);
                    acc[i][2] = fmaf(xv.z, w2.z, acc[i][2]);
                    acc[i][3] = fmaf(xv.z, w2.w, acc[i][3]);
                    acc[i][0] = fmaf(xv.w, w3.x, acc[i][0]);
                    acc[i][1] = fmaf(xv.w, w3.y, acc[i][1]);
                    acc[i][2] = fmaf(xv.w, w3.z, acc[i][2]);
                    acc[i][3] = fmaf(xv.w, w3.w, acc[i][3]);
                }
            }
            __syncthreads();   // xs reads done before next chunk overwrites

            // LIF for this chunk (arithmetic identical to prior passes)
            #pragma unroll
            for (int i = 0; i < CH; ++i) {
                const int t = tgc * CH + i;
                #pragma unroll
                for (int e = 0; e < 4; ++e) {
                    m[e] = m[e] + (acc[i][e] - m[e]) * 0.5f;
                    const float s = (m[e] - 1.0f > 0.0f) ? 1.0f : 0.0f;
                    mc[e] |= (s > 0.0f) ? (1u << t) : 0u;
                    m[e] *= (1.0f - s);
                }
            }
        }

        #pragma unroll
        for (int e = 0; e < 4; ++e) msk[tg * DD + e0 + e] = mc[e];
    }
    __syncthreads();

    // ================= Phase B: GEMM2 via bf16 MFMA =================
    // wave wv: token (wv>>1), t-half (wv&1). Round-7-verified per-wave path.
    {
        const int wv   = tid >> 6;            // 0..3
        const int lane = tid & 63;
        const int qB   = wv >> 1;             // token within block
        const int hB   = wv & 1;              // t-half
        const int lcol = lane & 15;
        const int lkg  = lane >> 4;           // 0..3
        const int tA   = hB * 16 + lcol;      // A-frag row (t) this lane supplies
        const size_t baseB = (size_t)(blockIdx.x * 2 + qB) * DD;
        const unsigned* mq = &msk[qB * DD];

        // --- build all 16 A-frags in-register from global x + LDS mask bits ---
        short8 af[16];
        #pragma unroll
        for (int ks = 0; ks < 16; ++ks) {
            const int kb = ks * 32 + lkg * 8;
            const float4 x0 = *reinterpret_cast<const float4*>(&x[(size_t)tA * st + baseB + kb]);
            const float4 x1 = *reinterpret_cast<const float4*>(&x[(size_t)tA * st + baseB + kb + 4]);
            const uint4 m0 = *reinterpret_cast<const uint4*>(&mq[kb]);
            const uint4 m1 = *reinterpret_cast<const uint4*>(&mq[kb + 4]);
            short8 a;
            a[0] = (short)f2bf(((m0.x >> tA) & 1u) ? 0.0f : x0.x);
            a[1] = (short)f2bf(((m0.y >> tA) & 1u) ? 0.0f : x0.y);
            a[2] = (short)f2bf(((m0.z >> tA) & 1u) ? 0.0f : x0.z);
            a[3] = (short)f2bf(((m0.w >> tA) & 1u) ? 0.0f : x0.w);
            a[4] = (short)f2bf(((m1.x >> tA) & 1u) ? 0.0f : x1.x);
            a[5] = (short)f2bf(((m1.y >> tA) & 1u) ? 0.0f : x1.y);
            a[6] = (short)f2bf(((m1.z >> tA) & 1u) ? 0.0f : x1.z);
            a[7] = (short)f2bf(((m1.w >> tA) & 1u) ? 0.0f : x1.w);
            af[ks] = a;
        }

        // --- 4 passes of 128 output cols; acc[8] tiles of 16 cols each ---
        #pragma unroll 1
        for (int pass = 0; pass < 4; ++pass) {
            const int colb = pass * 128;
            f32x4 acc[8];
            #pragma unroll
            for (int nt = 0; nt < 8; ++nt) {
                const float b = br[colb + nt * 16 + lcol];
                acc[nt] = (f32x4){b, b, b, b};
            }

            #pragma unroll
            for (int ks = 0; ks < 16; ++ks) {
                const int kb = ks * 32 + lkg * 8;
                #pragma unroll
                for (int nt = 0; nt < 8; ++nt) {
                    const int col = colb + nt * 16 + lcol;
                    short8 bf;
                    if (UW) {
                        bf = *reinterpret_cast<const short8*>(&Wt[(size_t)col * DD + kb]);
                    } else {
                        #pragma unroll
                        for (int j = 0; j < 8; ++j)
                            bf[j] = (short)f2bf(Wr[(size_t)(kb + j) * DD + col]);
                    }
                    acc[nt] = __builtin_amdgcn_mfma_f32_16x16x32_bf16(af[ks], bf, acc[nt], 0, 0, 0);
                }
            }

            // epilogue: C/D layout col=lane&15, row=(lane>>4)*4+r (verified r7)
            #pragma unroll
            for (int nt = 0; nt < 8; ++nt) {
                const int col = colb + nt * 16 + lcol;
                #pragma unroll
                for (int r = 0; r < 4; ++r) {
                    const int t = hB * 16 + lkg * 4 + r;
                    out[(size_t)t * st + baseB + col] = acc[nt][r];
                }
            }
        }
    }
}

extern "C" void kernel_launch(void* const* d_in, const int* in_sizes, int n_in,
                              void* d_out, int out_size, void* d_ws, size_t ws_size,
                              hipStream_t stream) {
    const float* x     = (const float*)d_in[0];
    const float* tr_mx = (const float*)d_in[1];
    const float* Wl    = (const float*)d_in[2];
    const float* bl    = (const float*)d_in[3];
    const float* Wr    = (const float*)d_in[4];
    const float* br    = (const float*)d_in[5];
    float* out = (float*)d_out;

    const size_t wt_bytes = (size_t)DD * DD * 2;
    dim3 grid(BB * NN / 2);   // 1024 two-token blocks
    dim3 block(256);

    if (ws_size >= wt_bytes) {
        unsigned short* Wt = (unsigned short*)d_ws;
        cast_transpose_wr<<<dim3(1024), dim3(256), 0, stream>>>(Wr, Wt);
        lif_decoder_v9<true><<<grid, block, 0, stream>>>(x, tr_mx, Wl, bl, Wr, br, Wt, out);
    } else {
        lif_decoder_v9<false><<<grid, block, 0, stream>>>(x, tr_mx, Wl, bl, Wr, br, nullptr, out);
    }
}

// Round 10
// 782.206 us; speedup vs baseline: 1.2486x; 1.0002x over previous
//
#include <hip/hip_runtime.h>
#include <hip/hip_bf16.h>

// Decoder_21208548508049 — round 10.
// r9 post-mortem: phase B STILL spilled (~120MB scratch writes) because
// af[16] (64 VGPR) + acc + bf pipeline > the 128-VGPR cap that arg2=2 yields.
// Fix (single change): rebuild the A-fragment per-ks inside each col-pass
// instead of prebuilding af[16]. Live set ~100 regs -> no spill. x rows are
// L1-hot after pass 0; conversions deterministic -> bit-identical numerics.
//
// Phase A: GEMM1 exact f32 FMA chain (spikes bit-identical, r1/4/5/6-proven)
//   + LIF -> bitmask. 2 tokens/block.
// Phase B: GEMM2 bf16 MFMA, A-frags in-register from global x + LDS mask.
//
// T=32,B=8,N=256,D=512. Block = 2 tokens, 256 threads (4 waves). Grid = 1024.
// LDS: xs[2][8][512] f32 (32KB) + msk[2][512] (4KB) = 36KB.

#define TT 32
#define CH 8     // t-chunk for phase A
#define BB 8
#define NN 256
#define DD 512

typedef __attribute__((ext_vector_type(8))) short short8;
typedef __attribute__((ext_vector_type(4))) float f32x4;

__device__ __forceinline__ unsigned short f2bf(float f) {
    __hip_bfloat16 h = __float2bfloat16(f);
    return *reinterpret_cast<unsigned short*>(&h);
}

// ---- pre-kernel: Wt[p][d] = bf16(Wr[d][p]) ----
__global__ void cast_transpose_wr(const float* __restrict__ Wr,
                                  unsigned short* __restrict__ Wt) {
    int idx = blockIdx.x * 256 + threadIdx.x;      // 0..262143
    int d = idx >> 9;
    int p = idx & 511;
    Wt[p * DD + d] = f2bf(Wr[idx]);
}

template<bool UW>
__global__ __launch_bounds__(256, 2) void lif_decoder_v10(
    const float* __restrict__ x,      // [T,B,N,D]
    const float* __restrict__ tr_mx,  // [B,N,D]
    const float* __restrict__ Wl,     // [D,D]
    const float* __restrict__ bl,     // [D]
    const float* __restrict__ Wr,     // [D,D]
    const float* __restrict__ br,     // [D]
    const unsigned short* __restrict__ Wt,  // [D,D] bf16 transposed (if UW)
    float* __restrict__ out)          // [T,B,N,D]
{
    __shared__ __align__(16) float xs[2 * CH * DD];    // 32 KB: 2 tokens x t-chunk
    __shared__ __align__(16) unsigned msk[2 * DD];     // 4 KB: (msk[q][d]>>t)&1

    const int tid = threadIdx.x;          // 0..255
    const int tg  = tid >> 7;             // token within block (0/1)
    const int tl  = tid & 127;
    const int e0  = tl * 4;               // owned e-columns (within own token)
    const int tok = blockIdx.x * 2 + tg;
    const size_t base = (size_t)tok * DD;
    const size_t st   = (size_t)BB * NN * DD;   // t-stride

    // ================= Phase A: GEMM1 + LIF =================
    {
        float acc[CH][4];
        float4 m4 = *reinterpret_cast<const float4*>(&tr_mx[base + e0]);
        float m[4] = {m4.x, m4.y, m4.z, m4.w};
        unsigned mc[4] = {0u, 0u, 0u, 0u};

        const float4 blv = *reinterpret_cast<const float4*>(&bl[e0]);
        const float blr[4] = {blv.x, blv.y, blv.z, blv.w};

        #pragma unroll 1
        for (int tgc = 0; tgc < 4; ++tgc) {
            // stage x[tgc*8..+7][both tokens][0..511]: 8 float4/thread, coalesced
            #pragma unroll
            for (int r = 0; r < 8; ++r) {
                const int flat = r * 256 + tid;        // 0..2047
                const int q    = flat >> 10;           // token 0/1
                const int rem  = flat & 1023;
                const int trow = rem >> 7;             // 0..7
                const int c4   = rem & 127;
                const float4 v = *reinterpret_cast<const float4*>(
                    &x[(size_t)(tgc * CH + trow) * st
                       + (size_t)(blockIdx.x * 2 + q) * DD + c4 * 4]);
                *reinterpret_cast<float4*>(&xs[(q * CH + trow) * DD + c4 * 4]) = v;
            }
            __syncthreads();

            #pragma unroll
            for (int i = 0; i < CH; ++i)
                #pragma unroll
                for (int e = 0; e < 4; ++e) acc[i][e] = blr[e];

            const float* xsl = &xs[tg * CH * DD];   // own token's tile

            #pragma unroll 2
            for (int d = 0; d < DD; d += 4) {
                const float4 w0 = *reinterpret_cast<const float4*>(&Wl[(size_t)(d + 0) * DD + e0]);
                const float4 w1 = *reinterpret_cast<const float4*>(&Wl[(size_t)(d + 1) * DD + e0]);
                const float4 w2 = *reinterpret_cast<const float4*>(&Wl[(size_t)(d + 2) * DD + e0]);
                const float4 w3 = *reinterpret_cast<const float4*>(&Wl[(size_t)(d + 3) * DD + e0]);
                #pragma unroll
                for (int i = 0; i < CH; ++i) {
                    const float4 xv = *reinterpret_cast<const float4*>(&xsl[i * DD + d]);
                    // d-ascending fmaf chain per (t,e): identical to r1/4/5/6 passes
                    acc[i][0] = fmaf(xv.x, w0.x, acc[i][0]);
                    acc[i][1] = fmaf(xv.x, w0.y, acc[i][1]);
                    acc[i][2] = fmaf(xv.x, w0.z, acc[i][2]);
                    acc[i][3] = fmaf(xv.x, w0.w, acc[i][3]);
                    acc[i][0] = fmaf(xv.y, w1.x, acc[i][0]);
                    acc[i][1] = fmaf(xv.y, w1.y, acc[i][1]);
                    acc[i][2] = fmaf(xv.y, w1.z, acc[i][2]);
                    acc[i][3] = fmaf(xv.y, w1.w, acc[i][3]);
                    acc[i][0] = fmaf(xv.z, w2.x, acc[i][0]);
                    acc[i][1] = fmaf(xv.z, w2.y, acc[i][1]);
                    acc[i][2] = fmaf(xv.z, w2.z, acc[i][2]);
                    acc[i][3] = fmaf(xv.z, w2.w, acc[i][3]);
                    acc[i][0] = fmaf(xv.w, w3.x, acc[i][0]);
                    acc[i][1] = fmaf(xv.w, w3.y, acc[i][1]);
                    acc[i][2] = fmaf(xv.w, w3.z, acc[i][2]);
                    acc[i][3] = fmaf(xv.w, w3.w, acc[i][3]);
                }
            }
            __syncthreads();   // xs reads done before next chunk overwrites

            // LIF for this chunk (arithmetic identical to prior passes)
            #pragma unroll
            for (int i = 0; i < CH; ++i) {
                const int t = tgc * CH + i;
                #pragma unroll
                for (int e = 0; e < 4; ++e) {
                    m[e] = m[e] + (acc[i][e] - m[e]) * 0.5f;
                    const float s = (m[e] - 1.0f > 0.0f) ? 1.0f : 0.0f;
                    mc[e] |= (s > 0.0f) ? (1u << t) : 0u;
                    m[e] *= (1.0f - s);
                }
            }
        }

        #pragma unroll
        for (int e = 0; e < 4; ++e) msk[tg * DD + e0 + e] = mc[e];
    }
    __syncthreads();

    // ================= Phase B: GEMM2 via bf16 MFMA =================
    // wave wv: token (wv>>1), t-half (wv&1). A-frag rebuilt per-ks (live set
    // ~100 regs < 128 cap -> no spill; x rows L1-hot after pass 0).
    {
        const int wv   = tid >> 6;            // 0..3
        const int lane = tid & 63;
        const int qB   = wv >> 1;             // token within block
        const int hB   = wv & 1;              // t-half
        const int lcol = lane & 15;
        const int lkg  = lane >> 4;           // 0..3
        const int tA   = hB * 16 + lcol;      // A-frag row (t) this lane supplies
        const size_t baseB = (size_t)(blockIdx.x * 2 + qB) * DD;
        const unsigned* mq = &msk[qB * DD];
        const float* xrow = &x[(size_t)tA * st + baseB];

        // --- 4 passes of 128 output cols; acc[8] tiles of 16 cols each ---
        #pragma unroll 1
        for (int pass = 0; pass < 4; ++pass) {
            const int colb = pass * 128;
            f32x4 acc[8];
            #pragma unroll
            for (int nt = 0; nt < 8; ++nt) {
                const float b = br[colb + nt * 16 + lcol];
                acc[nt] = (f32x4){b, b, b, b};
            }

            #pragma unroll
            for (int ks = 0; ks < 16; ++ks) {
                const int kb = ks * 32 + lkg * 8;
                // rebuild A-frag for this ks (deterministic -> bit-identical)
                const float4 x0 = *reinterpret_cast<const float4*>(&xrow[kb]);
                const float4 x1 = *reinterpret_cast<const float4*>(&xrow[kb + 4]);
                const uint4 m0 = *reinterpret_cast<const uint4*>(&mq[kb]);
                const uint4 m1 = *reinterpret_cast<const uint4*>(&mq[kb + 4]);
                short8 a;
                a[0] = (short)f2bf(((m0.x >> tA) & 1u) ? 0.0f : x0.x);
                a[1] = (short)f2bf(((m0.y >> tA) & 1u) ? 0.0f : x0.y);
                a[2] = (short)f2bf(((m0.z >> tA) & 1u) ? 0.0f : x0.z);
                a[3] = (short)f2bf(((m0.w >> tA) & 1u) ? 0.0f : x0.w);
                a[4] = (short)f2bf(((m1.x >> tA) & 1u) ? 0.0f : x1.x);
                a[5] = (short)f2bf(((m1.y >> tA) & 1u) ? 0.0f : x1.y);
                a[6] = (short)f2bf(((m1.z >> tA) & 1u) ? 0.0f : x1.z);
                a[7] = (short)f2bf(((m1.w >> tA) & 1u) ? 0.0f : x1.w);

                #pragma unroll
                for (int nt = 0; nt < 8; ++nt) {
                    const int col = colb + nt * 16 + lcol;
                    short8 bf;
                    if (UW) {
                        bf = *reinterpret_cast<const short8*>(&Wt[(size_t)col * DD + kb]);
                    } else {
                        #pragma unroll
                        for (int j = 0; j < 8; ++j)
                            bf[j] = (short)f2bf(Wr[(size_t)(kb + j) * DD + col]);
                    }
                    acc[nt] = __builtin_amdgcn_mfma_f32_16x16x32_bf16(a, bf, acc[nt], 0, 0, 0);
                }
            }

            // epilogue: C/D layout col=lane&15, row=(lane>>4)*4+r (verified r7)
            #pragma unroll
            for (int nt = 0; nt < 8; ++nt) {
                const int col = colb + nt * 16 + lcol;
                #pragma unroll
                for (int r = 0; r < 4; ++r) {
                    const int t = hB * 16 + lkg * 4 + r;
                    out[(size_t)t * st + baseB + col] = acc[nt][r];
                }
            }
        }
    }
}

extern "C" void kernel_launch(void* const* d_in, const int* in_sizes, int n_in,
                              void* d_out, int out_size, void* d_ws, size_t ws_size,
                              hipStream_t stream) {
    const float* x     = (const float*)d_in[0];
    const float* tr_mx = (const float*)d_in[1];
    const float* Wl    = (const float*)d_in[2];
    const float* bl    = (const float*)d_in[3];
    const float* Wr    = (const float*)d_in[4];
    const float* br    = (const float*)d_in[5];
    float* out = (float*)d_out;

    const size_t wt_bytes = (size_t)DD * DD * 2;
    dim3 grid(BB * NN / 2);   // 1024 two-token blocks
    dim3 block(256);

    if (ws_size >= wt_bytes) {
        unsigned short* Wt = (unsigned short*)d_ws;
        cast_transpose_wr<<<dim3(1024), dim3(256), 0, stream>>>(Wr, Wt);
        lif_decoder_v10<true><<<grid, block, 0, stream>>>(x, tr_mx, Wl, bl, Wr, br, Wt, out);
    } else {
        lif_decoder_v10<false><<<grid, block, 0, stream>>>(x, tr_mx, Wl, bl, Wr, br, nullptr, out);
    }
}